// Round 2
// baseline (251.710 us; speedup 1.0000x reference)
//
#include <hip/hip_runtime.h>
#include <stdint.h>

#define Bb 2
#define Ss 2048
#define Dd 1024
#define Hh 8
#define Ee 128
#define KWW 16
#define Mm (Bb*Ss)   // 4096
#define Kk 1024      // K for both GEMMs

typedef unsigned short u16;
typedef __attribute__((ext_vector_type(8))) short bf16x8;  // 8 bf16 (4 VGPRs)
typedef __attribute__((ext_vector_type(4))) float f32x4;

// fp32 -> bf16 round-to-nearest-even
__device__ __forceinline__ u16 f2bf(float f) {
  union { float f; uint32_t u; } v; v.f = f;
  return (u16)((v.u + 0x7FFFu + ((v.u >> 16) & 1u)) >> 16);
}
__device__ __forceinline__ float bf2f(u16 h) {
  union { uint32_t u; float f; } v; v.u = ((uint32_t)h) << 16; return v.f;
}

// async global->LDS, 16B per lane. LDS dst must be wave-uniform base; HW scatters lane*16B.
__device__ __forceinline__ void gll16(const void* g, void* l) {
  __builtin_amdgcn_global_load_lds((const __attribute__((address_space(1))) void*)g,
                                   (__attribute__((address_space(3))) void*)l, 16, 0, 0);
}

// ---------------- prep kernels ----------------

// x -> (hi, lo) bf16 pair: hi = bf16(x), lo = bf16(x - hi)
__global__ __launch_bounds__(256) void cast_split(const float* __restrict__ in,
                                                  u16* __restrict__ hi,
                                                  u16* __restrict__ lo, int n) {
  int i = (blockIdx.x * 256 + threadIdx.x) * 4;
  if (i < n) {
    float4 f = *(const float4*)(in + i);
    u16 h0 = f2bf(f.x), h1 = f2bf(f.y), h2 = f2bf(f.z), h3 = f2bf(f.w);
    u16 l0 = f2bf(f.x - bf2f(h0)), l1 = f2bf(f.y - bf2f(h1));
    u16 l2 = f2bf(f.z - bf2f(h2)), l3 = f2bf(f.w - bf2f(h3));
    *(uint64_t*)(hi + i) = (uint64_t)h0 | ((uint64_t)h1 << 16) | ((uint64_t)h2 << 32) | ((uint64_t)h3 << 48);
    *(uint64_t*)(lo + i) = (uint64_t)l0 | ((uint64_t)l1 << 16) | ((uint64_t)l2 << 32) | ((uint64_t)l3 << 48);
  }
}

// batched transpose [R][C] f32 -> [C][R] bf16 (R,C multiples of 32); optional lo output
template<bool SPLIT>
__global__ __launch_bounds__(256) void transpose_f32_bf16(
    const float* __restrict__ in, u16* __restrict__ hi, u16* __restrict__ lo,
    int R, int C, long inBatchStride, long outBatchStride) {
  __shared__ float tile[32][33];  // +1 pad: bank-conflict-free
  const float* ib = in + (size_t)blockIdx.z * inBatchStride;
  u16* hb = hi + (size_t)blockIdx.z * outBatchStride;
  u16* lb = SPLIT ? lo + (size_t)blockIdx.z * outBatchStride : nullptr;
  int r0 = blockIdx.x * 32, c0 = blockIdx.y * 32;
  int tx = threadIdx.x, ty = threadIdx.y;  // block (32,8)
  #pragma unroll
  for (int kq = 0; kq < 4; kq++)
    tile[ty + 8*kq][tx] = ib[(size_t)(r0 + ty + 8*kq) * C + (c0 + tx)];
  __syncthreads();
  #pragma unroll
  for (int kq = 0; kq < 4; kq++) {
    float f = tile[tx][ty + 8*kq];
    u16 h = f2bf(f);
    size_t idx = (size_t)(c0 + ty + 8*kq) * R + (r0 + tx);
    hb[idx] = h;
    if constexpr (SPLIT) lb[idx] = f2bf(f - bf2f(h));
  }
}

// ---------------- GEMM core: 128x128 tile, BK=32, 4 waves x (4x4) 16x16x32 MFMA ----------------
// A: [M][K] bf16 row-major; Bt: [N][K] bf16 row-major (B^T form).
// SPLIT: acc += Ahi*Bhi + Alo*Bhi + Ahi*Blo  (emulated-fp32, lo*lo dropped)
// LDS: As/Bs sized 128*32*(SPLIT?2:1); lo tiles at element offset 4096.
template<bool SPLIT>
__device__ __forceinline__ void gemm_core_128(
    const u16* __restrict__ Ahi, const u16* __restrict__ Alo,
    const u16* __restrict__ Bhi, const u16* __restrict__ Blo,
    u16* As, u16* Bs, f32x4 acc[4][4]) {
  const int tid = threadIdx.x;
  const int wave = tid >> 6;
  const int lane = tid & 63;
  // staging: row = wave*16 + lane/4 (rows 0..63 via l0, +64 via l1), 16B chunks along K
  const int srow = wave * 16 + (lane >> 2);
  const int skc  = (lane & 3) * 8;
  const size_t go0 = (size_t)srow        * Kk + skc;
  const size_t go1 = (size_t)(srow + 64) * Kk + skc;
  u16* al0 = As + wave * 512;          // wave-uniform LDS bases
  u16* al1 = As + 2048 + wave * 512;
  u16* bl0 = Bs + wave * 512;
  u16* bl1 = Bs + 2048 + wave * 512;

  const int wm = (wave >> 1) * 64;     // wave 2x2 arrangement -> 64x64 subtile
  const int wn = (wave & 1) * 64;
  const int fr = lane & 15;            // A: m-in-16 / B: n-in-16
  const int fk = (lane >> 4) * 8;      // k offset (quad*8)

  #pragma unroll
  for (int i = 0; i < 4; i++)
    #pragma unroll
    for (int j = 0; j < 4; j++)
      #pragma unroll
      for (int r = 0; r < 4; r++) acc[i][j][r] = 0.0f;

  for (int kt = 0; kt < Kk; kt += 32) {
    gll16(Ahi + go0 + kt, al0);
    gll16(Ahi + go1 + kt, al1);
    gll16(Bhi + go0 + kt, bl0);
    gll16(Bhi + go1 + kt, bl1);
    if constexpr (SPLIT) {
      gll16(Alo + go0 + kt, al0 + 4096);
      gll16(Alo + go1 + kt, al1 + 4096);
      gll16(Blo + go0 + kt, bl0 + 4096);
      gll16(Blo + go1 + kt, bl1 + 4096);
    }
    __syncthreads();   // drains vmcnt (global_load_lds) before LDS reads
    bf16x8 ah[4], bh[4];
    #pragma unroll
    for (int i = 0; i < 4; i++)
      ah[i] = *(const bf16x8*)(As + (wm + i * 16 + fr) * 32 + fk);
    #pragma unroll
    for (int j = 0; j < 4; j++)
      bh[j] = *(const bf16x8*)(Bs + (wn + j * 16 + fr) * 32 + fk);
    #pragma unroll
    for (int i = 0; i < 4; i++)
      #pragma unroll
      for (int j = 0; j < 4; j++)
        acc[i][j] = __builtin_amdgcn_mfma_f32_16x16x32_bf16(ah[i], bh[j], acc[i][j], 0, 0, 0);
    if constexpr (SPLIT) {
      {
        bf16x8 alx[4];
        #pragma unroll
        for (int i = 0; i < 4; i++)
          alx[i] = *(const bf16x8*)(As + 4096 + (wm + i * 16 + fr) * 32 + fk);
        #pragma unroll
        for (int i = 0; i < 4; i++)
          #pragma unroll
          for (int j = 0; j < 4; j++)
            acc[i][j] = __builtin_amdgcn_mfma_f32_16x16x32_bf16(alx[i], bh[j], acc[i][j], 0, 0, 0);
      }
      {
        bf16x8 blx[4];
        #pragma unroll
        for (int j = 0; j < 4; j++)
          blx[j] = *(const bf16x8*)(Bs + 4096 + (wn + j * 16 + fr) * 32 + fk);
        #pragma unroll
        for (int i = 0; i < 4; i++)
          #pragma unroll
          for (int j = 0; j < 4; j++)
            acc[i][j] = __builtin_amdgcn_mfma_f32_16x16x32_bf16(ah[i], blx[j], acc[i][j], 0, 0, 0);
      }
    }
    __syncthreads();   // ds_reads done before next staging overwrites LDS
  }
}

// C/D layout (measured m89/m91): col = lane&15, row = (lane>>4)*4 + reg

__global__ __launch_bounds__(256) void gemm_qkv(
    const u16* __restrict__ xhi, const u16* __restrict__ xlo,
    const u16* __restrict__ wThi, const u16* __restrict__ wTlo,
    const u16* __restrict__ wTv,
    const float* __restrict__ bq, const float* __restrict__ bk, const float* __restrict__ bv,
    float* __restrict__ q, float* __restrict__ k, float* __restrict__ v) {
  __shared__ u16 As[128 * 32 * 2];
  __shared__ u16 Bs[128 * 32 * 2];
  const int m0 = blockIdx.x * 128;
  const int z = blockIdx.z;            // proj*8 + h
  const int proj = z >> 3, h = z & 7;
  f32x4 acc[4][4];
  if (proj < 2) {
    gemm_core_128<true>(xhi + (size_t)m0 * Kk, xlo + (size_t)m0 * Kk,
                        wThi + (size_t)z * (Ee * Kk), wTlo + (size_t)z * (Ee * Kk),
                        As, Bs, acc);
  } else {
    gemm_core_128<false>(xhi + (size_t)m0 * Kk, nullptr,
                         wTv + (size_t)h * (Ee * Kk), nullptr, As, Bs, acc);
  }

  float* dst = proj == 0 ? q : (proj == 1 ? k : v);
  const float* bias = proj == 0 ? bq : (proj == 1 ? bk : bv);
  const int wave = threadIdx.x >> 6, lane = threadIdx.x & 63;
  const int wm = (wave >> 1) * 64, wn = (wave & 1) * 64;
  const int cn = lane & 15, rq4 = (lane >> 4) * 4;
  #pragma unroll
  for (int j = 0; j < 4; j++) {
    const int e = wn + j * 16 + cn;
    const float bb = bias[h * Ee + e];
    #pragma unroll
    for (int i = 0; i < 4; i++) {
      #pragma unroll
      for (int r = 0; r < 4; r++) {
        const int m = m0 + wm + i * 16 + rq4 + r;     // m = b*S + s
        const int b = m >> 11, s = m & (Ss - 1);
        dst[(((size_t)(b * Hh + h)) * Ss + s) * Ee + e] = acc[i][j][r] + bb;
      }
    }
  }
}

__global__ __launch_bounds__(256) void gemm_out(
    const u16* __restrict__ attn, const u16* __restrict__ woT,
    const float* __restrict__ bo, float* __restrict__ out) {
  __shared__ u16 As[128 * 32];
  __shared__ u16 Bs[128 * 32];
  const int m0 = blockIdx.x * 128;
  const int n0 = blockIdx.y * 128;
  f32x4 acc[4][4];
  gemm_core_128<false>(attn + (size_t)m0 * Kk, nullptr,
                       woT + (size_t)n0 * Kk, nullptr, As, Bs, acc);
  const int wave = threadIdx.x >> 6, lane = threadIdx.x & 63;
  const int wm = (wave >> 1) * 64, wn = (wave & 1) * 64;
  const int cn = lane & 15, rq4 = (lane >> 4) * 4;
  #pragma unroll
  for (int j = 0; j < 4; j++) {
    const int n = n0 + wn + j * 16 + cn;
    const float bb = bo[n];
    #pragma unroll
    for (int i = 0; i < 4; i++) {
      #pragma unroll
      for (int r = 0; r < 4; r++) {
        const int m = m0 + wm + i * 16 + rq4 + r;
        out[(size_t)m * Dd + n] = acc[i][j][r] + bb;
      }
    }
  }
}

// ---------------- attention: one wave per (b,h,s), fp32 throughout ----------------
__global__ __launch_bounds__(256) void attn_kernel(
    const float* __restrict__ q, const float* __restrict__ k, const float* __restrict__ v,
    const float* __restrict__ bk, const float* __restrict__ bv,
    const int* __restrict__ dil, u16* __restrict__ attn) {
  const int wid = blockIdx.x * 4 + (threadIdx.x >> 6);
  const int lane = threadIdx.x & 63;
  const int s = wid & (Ss - 1);
  const int bh = wid >> 11;          // b*H + h
  const int h = bh & 7, b = bh >> 3;
  const int d = dil[h];
  const size_t base = (size_t)bh * Ss * Ee;
  const float2* kp = (const float2*)(k + base);
  const float2* vp = (const float2*)(v + base);
  const float2 q2  = ((const float2*)(q + base + (size_t)s * Ee))[lane];
  const float2 bk2 = ((const float2*)(bk + h * Ee))[lane];
  const float2 bv2 = ((const float2*)(bv + h * Ee))[lane];
  const int off = (d * (KWW - 1)) >> 1;

  float logit[KWW];
  float2 vv[KWW];
  #pragma unroll
  for (int j = 0; j < KWW; j++) {
    const int pos = s + d * j - off;
    if (pos >= 0 && pos < Ss) {      // wave-uniform branch
      float2 kk = kp[(size_t)pos * 64 + lane];
      vv[j] = vp[(size_t)pos * 64 + lane];
      logit[j] = q2.x * kk.x + q2.y * kk.y;
    } else {
      vv[j] = bv2;
      logit[j] = q2.x * bk2.x + q2.y * bk2.y;  // padded key = bias (NOT masked)
    }
  }
  // 64-lane butterfly allreduce of all 16 logits
  #pragma unroll
  for (int o = 32; o > 0; o >>= 1)
    #pragma unroll
    for (int j = 0; j < KWW; j++)
      logit[j] += __shfl_xor(logit[j], o, 64);

  float mx = logit[0];
  #pragma unroll
  for (int j = 1; j < KWW; j++) mx = fmaxf(mx, logit[j]);
  float w[KWW], sum = 0.f;
  #pragma unroll
  for (int j = 0; j < KWW; j++) { w[j] = __expf(logit[j] - mx); sum += w[j]; }
  const float scale = 1.0f / (sum * 11.313708498984760f);  // /Z /sqrt(E), post-softmax quirk
  float ax = 0.f, ay = 0.f;
  #pragma unroll
  for (int j = 0; j < KWW; j++) { ax += w[j] * vv[j].x; ay += w[j] * vv[j].y; }
  ax *= scale; ay *= scale;
  // write bf16 attn as A-matrix [b*S+s][h*E+e]
  u16* op = attn + ((size_t)(b * Ss + s)) * (Hh * Ee) + h * Ee + 2 * lane;
  *(uint32_t*)op = (uint32_t)f2bf(ax) | ((uint32_t)f2bf(ay) << 16);
}

// ---------------- launcher ----------------
extern "C" void kernel_launch(void* const* d_in, const int* in_sizes, int n_in,
                              void* d_out, int out_size, void* d_ws, size_t ws_size,
                              hipStream_t stream) {
  (void)in_sizes; (void)n_in; (void)out_size; (void)ws_size;
  const float* x  = (const float*)d_in[0];
  const float* Wq = (const float*)d_in[1];
  const float* bq = (const float*)d_in[2];
  const float* Wk = (const float*)d_in[3];
  const float* bk = (const float*)d_in[4];
  const float* Wv = (const float*)d_in[5];
  const float* bv = (const float*)d_in[6];
  const float* Wo = (const float*)d_in[7];
  const float* bo = (const float*)d_in[8];
  const int* dil  = (const int*)d_in[9];
  float* out = (float*)d_out;

  char* ws = (char*)d_ws;
  u16* xhi  = (u16*)ws;  ws += (size_t)Mm * Kk * 2;            // 8 MB
  u16* xlo  = (u16*)ws;  ws += (size_t)Mm * Kk * 2;            // 8 MB
  u16* wThi = (u16*)ws;  ws += (size_t)16 * Ee * Kk * 2;       // 4 MB: [proj(q,k)][h][e][d]
  u16* wTlo = (u16*)ws;  ws += (size_t)16 * Ee * Kk * 2;       // 4 MB
  u16* wTv  = (u16*)ws;  ws += (size_t)Hh * Ee * Kk * 2;       // 2 MB: [h][e][d]
  u16* woT  = (u16*)ws;  ws += (size_t)Kk * Dd * 2;            // 2 MB: [d][h*E+e]
  float* q = (float*)ws; ws += (size_t)Bb * Hh * Ss * Ee * 4;  // 16 MB each
  float* k = (float*)ws; ws += (size_t)Bb * Hh * Ss * Ee * 4;
  float* v = (float*)ws; ws += (size_t)Bb * Hh * Ss * Ee * 4;
  // attn (8 MB bf16) aliases the xhi/xlo region — dead after gemm_qkv (stream-ordered)
  u16* attn = xhi;

  cast_split<<<(Mm * Kk) / 1024, 256, 0, stream>>>(x, xhi, xlo, Mm * Kk);
  dim3 tb(32, 8);
  // per-head [D][E] -> [E][D]; Wq,Wk split hi/lo, Wv plain
  transpose_f32_bf16<true><<<dim3(Dd / 32, Ee / 32, Hh), tb, 0, stream>>>(
      Wq, wThi + (size_t)0 * Hh * Ee * Kk, wTlo + (size_t)0 * Hh * Ee * Kk,
      Dd, Ee, (long)Dd * Ee, (long)Ee * Kk);
  transpose_f32_bf16<true><<<dim3(Dd / 32, Ee / 32, Hh), tb, 0, stream>>>(
      Wk, wThi + (size_t)1 * Hh * Ee * Kk, wTlo + (size_t)1 * Hh * Ee * Kk,
      Dd, Ee, (long)Dd * Ee, (long)Ee * Kk);
  transpose_f32_bf16<false><<<dim3(Dd / 32, Ee / 32, Hh), tb, 0, stream>>>(
      Wv, wTv, nullptr, Dd, Ee, (long)Dd * Ee, (long)Ee * Kk);
  // Wo [h*E][D] -> [D][h*E]
  transpose_f32_bf16<false><<<dim3((Hh * Ee) / 32, Dd / 32, 1), tb, 0, stream>>>(
      Wo, woT, nullptr, Hh * Ee, Dd, 0, 0);

  gemm_qkv<<<dim3(Mm / 128, 1, 24), 256, 0, stream>>>(
      xhi, xlo, wThi, wTlo, wTv, bq, bk, bv, q, k, v);
  attn_kernel<<<(Bb * Hh * Ss) / 4, 256, 0, stream>>>(q, k, v, bk, bv, dil, attn);
  gemm_out<<<dim3(Mm / 128, Dd / 128), 256, 0, stream>>>(attn, woT, bo, out);
}

// Round 3
// 218.735 us; speedup vs baseline: 1.1508x; 1.1508x over previous
//
#include <hip/hip_runtime.h>
#include <stdint.h>

#define Bb 2
#define Ss 2048
#define Dd 1024
#define Hh 8
#define Ee 128
#define KWW 16
#define Mm (Bb*Ss)   // 4096
#define Kk 1024      // K for both GEMMs

typedef unsigned short u16;
typedef __attribute__((ext_vector_type(8))) _Float16 f16x8;  // 8 fp16 (4 VGPRs)
typedef __attribute__((ext_vector_type(4))) float f32x4;

// fp32 -> fp16 (RTN)
__device__ __forceinline__ u16 f2h(float f) {
  union { _Float16 h; u16 u; } v; v.h = (_Float16)f; return v.u;
}

// async global->LDS, 16B per lane. LDS dst must be wave-uniform base; HW scatters lane*16B.
__device__ __forceinline__ void gll16(const void* g, void* l) {
  __builtin_amdgcn_global_load_lds((const __attribute__((address_space(1))) void*)g,
                                   (__attribute__((address_space(3))) void*)l, 16, 0, 0);
}

// ---------------- prep kernels ----------------

__global__ __launch_bounds__(256) void cast_f32_f16(const float* __restrict__ in,
                                                    u16* __restrict__ out, int n) {
  int i = (blockIdx.x * 256 + threadIdx.x) * 4;
  if (i < n) {
    float4 f = *(const float4*)(in + i);
    uint64_t pk = (uint64_t)f2h(f.x) | ((uint64_t)f2h(f.y) << 16) |
                  ((uint64_t)f2h(f.z) << 32) | ((uint64_t)f2h(f.w) << 48);
    *(uint64_t*)(out + i) = pk;
  }
}

// fused per-head transpose of Wq/Wk/Wv: [h][D][E] f32 -> wT[z][E][D] f16, z = proj*8+h
__global__ __launch_bounds__(256) void transpose_qkv(
    const float* __restrict__ Wq, const float* __restrict__ Wk,
    const float* __restrict__ Wv, u16* __restrict__ wT) {
  __shared__ float tile[32][33];  // +1 pad: bank-conflict-free
  const int z = blockIdx.z, h = z & 7;
  const float* W = (z < 8) ? Wq : (z < 16) ? Wk : Wv;
  const float* ib = W + (size_t)h * Dd * Ee;
  u16* ob = wT + (size_t)z * Ee * Kk;
  int r0 = blockIdx.x * 32, c0 = blockIdx.y * 32;   // r over D, c over E
  int tx = threadIdx.x, ty = threadIdx.y;  // block (32,8)
  #pragma unroll
  for (int kq = 0; kq < 4; kq++)
    tile[ty + 8*kq][tx] = ib[(size_t)(r0 + ty + 8*kq) * Ee + (c0 + tx)];
  __syncthreads();
  #pragma unroll
  for (int kq = 0; kq < 4; kq++)
    ob[(size_t)(c0 + ty + 8*kq) * Dd + (r0 + tx)] = f2h(tile[tx][ty + 8*kq]);
}

// Wo [h*E][D] f32 -> woT [D][h*E] f16
__global__ __launch_bounds__(256) void transpose_wo(
    const float* __restrict__ in, u16* __restrict__ out) {
  __shared__ float tile[32][33];
  const int R = Hh * Ee, C = Dd;
  int r0 = blockIdx.x * 32, c0 = blockIdx.y * 32;
  int tx = threadIdx.x, ty = threadIdx.y;
  #pragma unroll
  for (int kq = 0; kq < 4; kq++)
    tile[ty + 8*kq][tx] = in[(size_t)(r0 + ty + 8*kq) * C + (c0 + tx)];
  __syncthreads();
  #pragma unroll
  for (int kq = 0; kq < 4; kq++)
    out[(size_t)(c0 + ty + 8*kq) * R + (r0 + tx)] = f2h(tile[tx][ty + 8*kq]);
}

// ---------------- GEMM core: MTx128 tile, BK=32, 4 waves, 16x16x32 f16 MFMA ----------------
// A: [M][K] f16 row-major; Bt: [N][K] f16 row-major (B^T form).
template<int MT>   // 128 or 64
__device__ __forceinline__ void gemm_core(
    const u16* __restrict__ A, const u16* __restrict__ Bt,
    u16* As, u16* Bs, f32x4 (&acc)[MT / 32][4]) {
  constexpr int MI = MT / 32;
  const int tid = threadIdx.x;
  const int wave = tid >> 6;
  const int lane = tid & 63;
  // staging: row = wave*16 + lane/4 (rows 0..63 via *0, +64 via *1), 16B chunks along K
  const int srow = wave * 16 + (lane >> 2);
  const int skc  = (lane & 3) * 8;
  const size_t go0 = (size_t)srow        * Kk + skc;
  const size_t go1 = (size_t)(srow + 64) * Kk + skc;
  u16* al0 = As + wave * 512;          // wave-uniform LDS bases
  u16* al1 = As + 2048 + wave * 512;
  u16* bl0 = Bs + wave * 512;
  u16* bl1 = Bs + 2048 + wave * 512;

  const int wm = (wave >> 1) * (MT / 2);  // wave 2x2 arrangement
  const int wn = (wave & 1) * 64;
  const int fr = lane & 15;            // A: m-in-16 / B: n-in-16
  const int fk = (lane >> 4) * 8;      // k offset (quad*8)

  #pragma unroll
  for (int i = 0; i < MI; i++)
    #pragma unroll
    for (int j = 0; j < 4; j++)
      #pragma unroll
      for (int r = 0; r < 4; r++) acc[i][j][r] = 0.0f;

  for (int kt = 0; kt < Kk; kt += 32) {
    gll16(A + go0 + kt, al0);
    if constexpr (MT == 128) gll16(A + go1 + kt, al1);
    gll16(Bt + go0 + kt, bl0);
    gll16(Bt + go1 + kt, bl1);
    __syncthreads();   // drains vmcnt (global_load_lds) before LDS reads
    f16x8 ah[MI], bh[4];
    #pragma unroll
    for (int i = 0; i < MI; i++)
      ah[i] = *(const f16x8*)(As + (wm + i * 16 + fr) * 32 + fk);
    #pragma unroll
    for (int j = 0; j < 4; j++)
      bh[j] = *(const f16x8*)(Bs + (wn + j * 16 + fr) * 32 + fk);
    #pragma unroll
    for (int i = 0; i < MI; i++)
      #pragma unroll
      for (int j = 0; j < 4; j++)
        acc[i][j] = __builtin_amdgcn_mfma_f32_16x16x32_f16(ah[i], bh[j], acc[i][j], 0, 0, 0);
    __syncthreads();   // ds_reads done before next staging overwrites LDS
  }
}

// C/D layout (measured m89/m91): col = lane&15, row = (lane>>4)*4 + reg

__global__ __launch_bounds__(256) void gemm_qkv(
    const u16* __restrict__ xh, const u16* __restrict__ wT,
    const float* __restrict__ bq, const float* __restrict__ bk, const float* __restrict__ bv,
    float* __restrict__ q, float* __restrict__ k, float* __restrict__ v) {
  __shared__ u16 As[128 * 32];
  __shared__ u16 Bs[128 * 32];
  const int m0 = blockIdx.x * 128;
  const int z = blockIdx.z;            // proj*8 + h
  const int proj = z >> 3, h = z & 7;
  f32x4 acc[4][4];
  gemm_core<128>(xh + (size_t)m0 * Kk, wT + (size_t)z * (Ee * Kk), As, Bs, acc);

  float* dst = proj == 0 ? q : (proj == 1 ? k : v);
  const float* bias = proj == 0 ? bq : (proj == 1 ? bk : bv);
  const int wave = threadIdx.x >> 6, lane = threadIdx.x & 63;
  const int wm = (wave >> 1) * 64, wn = (wave & 1) * 64;
  const int cn = lane & 15, rq4 = (lane >> 4) * 4;
  #pragma unroll
  for (int j = 0; j < 4; j++) {
    const int e = wn + j * 16 + cn;
    const float bb = bias[h * Ee + e];
    #pragma unroll
    for (int i = 0; i < 4; i++) {
      #pragma unroll
      for (int r = 0; r < 4; r++) {
        const int m = m0 + wm + i * 16 + rq4 + r;     // m = b*S + s
        const int b = m >> 11, s = m & (Ss - 1);
        dst[(((size_t)(b * Hh + h)) * Ss + s) * Ee + e] = acc[i][j][r] + bb;
      }
    }
  }
}

__global__ __launch_bounds__(256) void gemm_out(
    const u16* __restrict__ attn, const u16* __restrict__ woT,
    const float* __restrict__ bo, float* __restrict__ out) {
  __shared__ u16 As[64 * 32];
  __shared__ u16 Bs[128 * 32];
  const int m0 = blockIdx.x * 64;
  const int n0 = blockIdx.y * 128;
  f32x4 acc[2][4];
  gemm_core<64>(attn + (size_t)m0 * Kk, woT + (size_t)n0 * Kk, As, Bs, acc);
  const int wave = threadIdx.x >> 6, lane = threadIdx.x & 63;
  const int wm = (wave >> 1) * 32, wn = (wave & 1) * 64;
  const int cn = lane & 15, rq4 = (lane >> 4) * 4;
  #pragma unroll
  for (int j = 0; j < 4; j++) {
    const int n = n0 + wn + j * 16 + cn;
    const float bb = bo[n];
    #pragma unroll
    for (int i = 0; i < 2; i++) {
      #pragma unroll
      for (int r = 0; r < 4; r++) {
        const int m = m0 + wm + i * 16 + rq4 + r;
        out[(size_t)m * Dd + n] = acc[i][j][r] + bb;
      }
    }
  }
}

// ---------------- attention: one wave per (b,h,s), fp32 throughout ----------------
__global__ __launch_bounds__(256) void attn_kernel(
    const float* __restrict__ q, const float* __restrict__ k, const float* __restrict__ v,
    const float* __restrict__ bk, const float* __restrict__ bv,
    const int* __restrict__ dil, u16* __restrict__ attn) {
  const int wid = blockIdx.x * 4 + (threadIdx.x >> 6);
  const int lane = threadIdx.x & 63;
  const int s = wid & (Ss - 1);
  const int bh = wid >> 11;          // b*H + h
  const int h = bh & 7, b = bh >> 3;
  const int d = dil[h];
  const size_t base = (size_t)bh * Ss * Ee;
  const float2* kp = (const float2*)(k + base);
  const float2* vp = (const float2*)(v + base);
  const float2 q2  = ((const float2*)(q + base + (size_t)s * Ee))[lane];
  const float2 bk2 = ((const float2*)(bk + h * Ee))[lane];
  const float2 bv2 = ((const float2*)(bv + h * Ee))[lane];
  const int off = (d * (KWW - 1)) >> 1;

  float logit[KWW];
  float2 vv[KWW];
  #pragma unroll
  for (int j = 0; j < KWW; j++) {
    const int pos = s + d * j - off;
    if (pos >= 0 && pos < Ss) {      // wave-uniform branch
      float2 kk = kp[(size_t)pos * 64 + lane];
      vv[j] = vp[(size_t)pos * 64 + lane];
      logit[j] = q2.x * kk.x + q2.y * kk.y;
    } else {
      vv[j] = bv2;
      logit[j] = q2.x * bk2.x + q2.y * bk2.y;  // padded key = bias (NOT masked)
    }
  }
  // 64-lane butterfly allreduce of all 16 logits
  #pragma unroll
  for (int o = 32; o > 0; o >>= 1)
    #pragma unroll
    for (int j = 0; j < KWW; j++)
      logit[j] += __shfl_xor(logit[j], o, 64);

  float mx = logit[0];
  #pragma unroll
  for (int j = 1; j < KWW; j++) mx = fmaxf(mx, logit[j]);
  float w[KWW], sum = 0.f;
  #pragma unroll
  for (int j = 0; j < KWW; j++) { w[j] = __expf(logit[j] - mx); sum += w[j]; }
  const float scale = 1.0f / (sum * 11.313708498984760f);  // /Z /sqrt(E), post-softmax quirk
  float ax = 0.f, ay = 0.f;
  #pragma unroll
  for (int j = 0; j < KWW; j++) { ax += w[j] * vv[j].x; ay += w[j] * vv[j].y; }
  ax *= scale; ay *= scale;
  // write fp16 attn as A-matrix [b*S+s][h*E+e]
  u16* op = attn + ((size_t)(b * Ss + s)) * (Hh * Ee) + h * Ee + 2 * lane;
  *(uint32_t*)op = (uint32_t)f2h(ax) | ((uint32_t)f2h(ay) << 16);
}

// ---------------- launcher ----------------
extern "C" void kernel_launch(void* const* d_in, const int* in_sizes, int n_in,
                              void* d_out, int out_size, void* d_ws, size_t ws_size,
                              hipStream_t stream) {
  (void)in_sizes; (void)n_in; (void)out_size; (void)ws_size;
  const float* x  = (const float*)d_in[0];
  const float* Wq = (const float*)d_in[1];
  const float* bq = (const float*)d_in[2];
  const float* Wk = (const float*)d_in[3];
  const float* bk = (const float*)d_in[4];
  const float* Wv = (const float*)d_in[5];
  const float* bv = (const float*)d_in[6];
  const float* Wo = (const float*)d_in[7];
  const float* bo = (const float*)d_in[8];
  const int* dil  = (const int*)d_in[9];
  float* out = (float*)d_out;

  char* ws = (char*)d_ws;
  u16* xh  = (u16*)ws;  ws += (size_t)Mm * Kk * 2;             // 8 MB  [m][d] f16
  u16* wT  = (u16*)ws;  ws += (size_t)24 * Ee * Kk * 2;        // 6 MB  [proj*8+h][e][d] f16
  u16* woT = (u16*)ws;  ws += (size_t)Kk * Dd * 2;             // 2 MB  [d][h*E+e] f16
  float* q = (float*)ws; ws += (size_t)Bb * Hh * Ss * Ee * 4;  // 16 MB each
  float* k = (float*)ws; ws += (size_t)Bb * Hh * Ss * Ee * 4;
  float* v = (float*)ws; ws += (size_t)Bb * Hh * Ss * Ee * 4;
  // attn (8 MB f16) aliases xh — dead after gemm_qkv (stream-ordered)
  u16* attn = xh;

  cast_f32_f16<<<(Mm * Kk) / 1024, 256, 0, stream>>>(x, xh, Mm * Kk);
  dim3 tb(32, 8);
  transpose_qkv<<<dim3(Dd / 32, Ee / 32, 24), tb, 0, stream>>>(Wq, Wk, Wv, wT);
  transpose_wo<<<dim3((Hh * Ee) / 32, Dd / 32, 1), tb, 0, stream>>>(Wo, woT);

  gemm_qkv<<<dim3(Mm / 128, 1, 24), 256, 0, stream>>>(xh, wT, bq, bk, bv, q, k, v);
  attn_kernel<<<(Bb * Hh * Ss) / 4, 256, 0, stream>>>(q, k, v, bk, bv, dil, attn);
  gemm_out<<<dim3(Mm / 64, Dd / 128), 256, 0, stream>>>(attn, woT, bo, out);
}

// Round 4
// 179.855 us; speedup vs baseline: 1.3995x; 1.2162x over previous
//
#include <hip/hip_runtime.h>
#include <stdint.h>

#define Bb 2
#define Ss 2048
#define Dd 1024
#define Hh 8
#define Ee 128
#define KWW 16
#define Mm (Bb*Ss)   // 4096
#define Kk 1024      // K for both GEMMs

typedef unsigned short u16;
typedef __attribute__((ext_vector_type(8))) _Float16 f16x8;  // 8 fp16 (4 VGPRs)
typedef __attribute__((ext_vector_type(4))) float f32x4;

// fp32 -> fp16 (RTN)
__device__ __forceinline__ u16 f2h(float f) {
  union { _Float16 h; u16 u; } v; v.h = (_Float16)f; return v.u;
}
__device__ __forceinline__ float h2f(u16 u) {
  union { u16 u; _Float16 h; } v; v.u = u; return (float)v.h;
}
__device__ __forceinline__ float h2f_lo(uint32_t w) { return h2f((u16)(w & 0xFFFF)); }
__device__ __forceinline__ float h2f_hi(uint32_t w) { return h2f((u16)(w >> 16)); }

// async global->LDS, 16B per lane. LDS dst must be wave-uniform base; HW scatters lane*16B.
__device__ __forceinline__ void gll16(const void* g, void* l) {
  __builtin_amdgcn_global_load_lds((const __attribute__((address_space(1))) void*)g,
                                   (__attribute__((address_space(3))) void*)l, 16, 0, 0);
}

// ---------------- prep kernels ----------------

__global__ __launch_bounds__(256) void cast_f32_f16(const float* __restrict__ in,
                                                    u16* __restrict__ out, int n) {
  int i = (blockIdx.x * 256 + threadIdx.x) * 4;
  if (i < n) {
    float4 f = *(const float4*)(in + i);
    uint64_t pk = (uint64_t)f2h(f.x) | ((uint64_t)f2h(f.y) << 16) |
                  ((uint64_t)f2h(f.z) << 32) | ((uint64_t)f2h(f.w) << 48);
    *(uint64_t*)(out + i) = pk;
  }
}

// fused per-head transpose of Wq/Wk/Wv: [h][D][E] f32 -> wT[z][E][D] f16, z = proj*8+h
__global__ __launch_bounds__(256) void transpose_qkv(
    const float* __restrict__ Wq, const float* __restrict__ Wk,
    const float* __restrict__ Wv, u16* __restrict__ wT) {
  __shared__ float tile[32][33];  // +1 pad: bank-conflict-free
  const int z = blockIdx.z, h = z & 7;
  const float* W = (z < 8) ? Wq : (z < 16) ? Wk : Wv;
  const float* ib = W + (size_t)h * Dd * Ee;
  u16* ob = wT + (size_t)z * Ee * Kk;
  int r0 = blockIdx.x * 32, c0 = blockIdx.y * 32;   // r over D, c over E
  int tx = threadIdx.x, ty = threadIdx.y;  // block (32,8)
  #pragma unroll
  for (int kq = 0; kq < 4; kq++)
    tile[ty + 8*kq][tx] = ib[(size_t)(r0 + ty + 8*kq) * Ee + (c0 + tx)];
  __syncthreads();
  #pragma unroll
  for (int kq = 0; kq < 4; kq++)
    ob[(size_t)(c0 + ty + 8*kq) * Dd + (r0 + tx)] = f2h(tile[tx][ty + 8*kq]);
}

// Wo [h*E][D] f32 -> woT [D][h*E] f16
__global__ __launch_bounds__(256) void transpose_wo(
    const float* __restrict__ in, u16* __restrict__ out) {
  __shared__ float tile[32][33];
  const int R = Hh * Ee, C = Dd;
  int r0 = blockIdx.x * 32, c0 = blockIdx.y * 32;
  int tx = threadIdx.x, ty = threadIdx.y;
  #pragma unroll
  for (int kq = 0; kq < 4; kq++)
    tile[ty + 8*kq][tx] = in[(size_t)(r0 + ty + 8*kq) * C + (c0 + tx)];
  __syncthreads();
  #pragma unroll
  for (int kq = 0; kq < 4; kq++)
    out[(size_t)(c0 + ty + 8*kq) * R + (r0 + tx)] = f2h(tile[tx][ty + 8*kq]);
}

// ---------------- GEMM core: MTx128 tile, BK=32, 4 waves, 16x16x32 f16 MFMA ----------------
// A: [M][K] f16 row-major; Bt: [N][K] f16 row-major (B^T form).
template<int MT>   // 128 or 64
__device__ __forceinline__ void gemm_core(
    const u16* __restrict__ A, const u16* __restrict__ Bt,
    u16* As, u16* Bs, f32x4 (&acc)[MT / 32][4]) {
  constexpr int MI = MT / 32;
  const int tid = threadIdx.x;
  const int wave = tid >> 6;
  const int lane = tid & 63;
  // staging: row = wave*16 + lane/4 (rows 0..63 via *0, +64 via *1), 16B chunks along K
  const int srow = wave * 16 + (lane >> 2);
  const int skc  = (lane & 3) * 8;
  const size_t go0 = (size_t)srow        * Kk + skc;
  const size_t go1 = (size_t)(srow + 64) * Kk + skc;
  u16* al0 = As + wave * 512;          // wave-uniform LDS bases
  u16* al1 = As + 2048 + wave * 512;
  u16* bl0 = Bs + wave * 512;
  u16* bl1 = Bs + 2048 + wave * 512;

  const int wm = (wave >> 1) * (MT / 2);  // wave 2x2 arrangement
  const int wn = (wave & 1) * 64;
  const int fr = lane & 15;            // A: m-in-16 / B: n-in-16
  const int fk = (lane >> 4) * 8;      // k offset (quad*8)

  #pragma unroll
  for (int i = 0; i < MI; i++)
    #pragma unroll
    for (int j = 0; j < 4; j++)
      #pragma unroll
      for (int r = 0; r < 4; r++) acc[i][j][r] = 0.0f;

  for (int kt = 0; kt < Kk; kt += 32) {
    gll16(A + go0 + kt, al0);
    if constexpr (MT == 128) gll16(A + go1 + kt, al1);
    gll16(Bt + go0 + kt, bl0);
    gll16(Bt + go1 + kt, bl1);
    __syncthreads();   // drains vmcnt (global_load_lds) before LDS reads
    f16x8 ah[MI], bh[4];
    #pragma unroll
    for (int i = 0; i < MI; i++)
      ah[i] = *(const f16x8*)(As + (wm + i * 16 + fr) * 32 + fk);
    #pragma unroll
    for (int j = 0; j < 4; j++)
      bh[j] = *(const f16x8*)(Bs + (wn + j * 16 + fr) * 32 + fk);
    #pragma unroll
    for (int i = 0; i < MI; i++)
      #pragma unroll
      for (int j = 0; j < 4; j++)
        acc[i][j] = __builtin_amdgcn_mfma_f32_16x16x32_f16(ah[i], bh[j], acc[i][j], 0, 0, 0);
    __syncthreads();   // ds_reads done before next staging overwrites LDS
  }
}

// C/D layout (measured m89/m91): col = lane&15, row = (lane>>4)*4 + reg

__global__ __launch_bounds__(256) void gemm_qkv(
    const u16* __restrict__ xh, const u16* __restrict__ wT,
    const float* __restrict__ bq, const float* __restrict__ bk, const float* __restrict__ bv,
    u16* __restrict__ q, u16* __restrict__ k, u16* __restrict__ v) {
  __shared__ u16 As[128 * 32];
  __shared__ u16 Bs[128 * 32];
  const int m0 = blockIdx.x * 128;
  const int z = blockIdx.z;            // proj*8 + h
  const int proj = z >> 3, h = z & 7;
  f32x4 acc[4][4];
  gemm_core<128>(xh + (size_t)m0 * Kk, wT + (size_t)z * (Ee * Kk), As, Bs, acc);

  u16* dst = proj == 0 ? q : (proj == 1 ? k : v);
  const float* bias = proj == 0 ? bq : (proj == 1 ? bk : bv);
  const int wave = threadIdx.x >> 6, lane = threadIdx.x & 63;
  const int wm = (wave >> 1) * 64, wn = (wave & 1) * 64;
  const int cn = lane & 15, rq4 = (lane >> 4) * 4;
  #pragma unroll
  for (int j = 0; j < 4; j++) {
    const int e = wn + j * 16 + cn;
    const float bb = bias[h * Ee + e];
    #pragma unroll
    for (int i = 0; i < 4; i++) {
      #pragma unroll
      for (int r = 0; r < 4; r++) {
        const int m = m0 + wm + i * 16 + rq4 + r;     // m = b*S + s
        const int b = m >> 11, s = m & (Ss - 1);
        dst[(((size_t)(b * Hh + h)) * Ss + s) * Ee + e] = f2h(acc[i][j][r] + bb);
      }
    }
  }
}

__global__ __launch_bounds__(256) void gemm_out(
    const u16* __restrict__ attn, const u16* __restrict__ woT,
    const float* __restrict__ bo, float* __restrict__ out) {
  __shared__ u16 As[64 * 32];
  __shared__ u16 Bs[128 * 32];
  const int m0 = blockIdx.x * 64;
  const int n0 = blockIdx.y * 128;
  f32x4 acc[2][4];
  gemm_core<64>(attn + (size_t)m0 * Kk, woT + (size_t)n0 * Kk, As, Bs, acc);
  const int wave = threadIdx.x >> 6, lane = threadIdx.x & 63;
  const int wm = (wave >> 1) * 32, wn = (wave & 1) * 64;
  const int cn = lane & 15, rq4 = (lane >> 4) * 4;
  #pragma unroll
  for (int j = 0; j < 4; j++) {
    const int n = n0 + wn + j * 16 + cn;
    const float bb = bo[n];
    #pragma unroll
    for (int i = 0; i < 2; i++) {
      #pragma unroll
      for (int r = 0; r < 4; r++) {
        const int m = m0 + wm + i * 16 + rq4 + r;
        out[(size_t)m * Dd + n] = acc[i][j][r] + bb;
      }
    }
  }
}

// ---------------- attention: one wave per (b,h,s), fp16 loads, fp32 math ----------------
// Cross-lane plan: reduce-scatter (17 sh) -> per-lane logit j=(lane>>2) -> max/sum
// butterflies (8 sh) -> 1 exp -> allgather weights (15 sh). v rows loaded in J^t
// order so every register index is compile-time.
__global__ __launch_bounds__(256) void attn_kernel(
    const u16* __restrict__ q, const u16* __restrict__ k, const u16* __restrict__ v,
    const float* __restrict__ bk, const float* __restrict__ bv,
    const int* __restrict__ dil, u16* __restrict__ attn) {
  // XCD-contiguous swizzle: XCD i (= blockIdx%8 round-robin) gets a contiguous
  // wid range = 2 whole (b,h) panels -> disjoint ~5MB L2 working set per XCD.
  const int nblk = (Bb * Hh * Ss) / 4;           // 8192
  const int blk = (blockIdx.x & 7) * (nblk / 8) + (blockIdx.x >> 3);
  const int wid = blk * 4 + (threadIdx.x >> 6);
  const int lane = threadIdx.x & 63;
  const int s = wid & (Ss - 1);
  const int bh = wid >> 11;          // b*H + h
  const int h = bh & 7, b = bh >> 3;
  const int d = dil[h];
  const size_t base = (size_t)bh * Ss * Ee;      // u16 elements
  const u16* kp = k + base;
  const u16* vp = v + base;
  const uint32_t qw = *(const uint32_t*)(q + base + (size_t)s * Ee + 2 * lane);
  const float qx = h2f_lo(qw), qy = h2f_hi(qw);
  const float2 bk2 = ((const float2*)(bk + h * Ee))[lane];
  const float2 bv2 = ((const float2*)(bv + h * Ee))[lane];
  const int off = (d * (KWW - 1)) >> 1;
  const int J = (lane >> 2) & 15;

  // ---- logit partials (absolute j; in-window test is wave-uniform) ----
  float logit[KWW];
  #pragma unroll
  for (int j = 0; j < KWW; j++) {
    const int pos = s + d * j - off;
    if (pos >= 0 && pos < Ss) {
      uint32_t kw = *(const uint32_t*)(kp + (size_t)pos * Ee + 2 * lane);
      logit[j] = qx * h2f_lo(kw) + qy * h2f_hi(kw);
    } else {
      logit[j] = qx * bk2.x + qy * bk2.y;  // padded key = bias (NOT masked)
    }
  }
  // ---- v rows in J^t order (per-lane J; clamp+select, no divergent loads) ----
  float vvx[KWW], vvy[KWW];
  #pragma unroll
  for (int t = 0; t < KWW; t++) {
    const int j = J ^ t;
    const int pos = s + d * j - off;
    const int posc = min(max(pos, 0), Ss - 1);
    uint32_t vw = *(const uint32_t*)(vp + (size_t)posc * Ee + 2 * lane);
    const bool ok = (pos >= 0) && (pos < Ss);
    vvx[t] = ok ? h2f_lo(vw) : bv2.x;
    vvy[t] = ok ? h2f_hi(vw) : bv2.y;
  }

  // ---- reduce-scatter: 16 vals over 64 lanes -> lane owns j = (lane>>2) ----
  {
    const bool hi = (lane & 32) != 0;
    #pragma unroll
    for (int j = 0; j < 8; j++) {
      float send = hi ? logit[j] : logit[j + 8];
      float recv = __shfl_xor(send, 32, 64);
      logit[j] = (hi ? logit[j + 8] : logit[j]) + recv;
    }
  }
  {
    const bool hi = (lane & 16) != 0;
    #pragma unroll
    for (int j = 0; j < 4; j++) {
      float send = hi ? logit[j] : logit[j + 4];
      float recv = __shfl_xor(send, 16, 64);
      logit[j] = (hi ? logit[j + 4] : logit[j]) + recv;
    }
  }
  {
    const bool hi = (lane & 8) != 0;
    #pragma unroll
    for (int j = 0; j < 2; j++) {
      float send = hi ? logit[j] : logit[j + 2];
      float recv = __shfl_xor(send, 8, 64);
      logit[j] = (hi ? logit[j + 2] : logit[j]) + recv;
    }
  }
  float own;
  {
    const bool hi = (lane & 4) != 0;
    float send = hi ? logit[0] : logit[1];
    float recv = __shfl_xor(send, 4, 64);
    own = (hi ? logit[1] : logit[0]) + recv;
  }
  own += __shfl_xor(own, 2, 64);
  own += __shfl_xor(own, 1, 64);   // own = full logit for j = J, replicated x4

  // ---- softmax over j (j lives on lane groups; bits 0,1 already uniform) ----
  float mx = own;
  mx = fmaxf(mx, __shfl_xor(mx, 4, 64));
  mx = fmaxf(mx, __shfl_xor(mx, 8, 64));
  mx = fmaxf(mx, __shfl_xor(mx, 16, 64));
  mx = fmaxf(mx, __shfl_xor(mx, 32, 64));
  float w = __expf(own - mx);
  float sum = w;
  sum += __shfl_xor(sum, 4, 64);
  sum += __shfl_xor(sum, 8, 64);
  sum += __shfl_xor(sum, 16, 64);
  sum += __shfl_xor(sum, 32, 64);
  w *= 1.0f / (sum * 11.313708498984760f);  // /Z /sqrt(E), post-softmax quirk

  // ---- allgather: g[t] = w[J^t] ----
  float g[KWW];
  g[0] = w;
  g[1] = __shfl_xor(g[0], 4, 64);
  #pragma unroll
  for (int t = 0; t < 2; t++) g[2 + t] = __shfl_xor(g[t], 8, 64);
  #pragma unroll
  for (int t = 0; t < 4; t++) g[4 + t] = __shfl_xor(g[t], 16, 64);
  #pragma unroll
  for (int t = 0; t < 8; t++) g[8 + t] = __shfl_xor(g[t], 32, 64);

  float ax = 0.f, ay = 0.f;
  #pragma unroll
  for (int t = 0; t < KWW; t++) { ax += g[t] * vvx[t]; ay += g[t] * vvy[t]; }

  // write fp16 attn as A-matrix [b*S+s][h*E+e]
  u16* op = attn + ((size_t)(b * Ss + s)) * (Hh * Ee) + h * Ee + 2 * lane;
  *(uint32_t*)op = (uint32_t)f2h(ax) | ((uint32_t)f2h(ay) << 16);
}

// ---------------- launcher ----------------
extern "C" void kernel_launch(void* const* d_in, const int* in_sizes, int n_in,
                              void* d_out, int out_size, void* d_ws, size_t ws_size,
                              hipStream_t stream) {
  (void)in_sizes; (void)n_in; (void)out_size; (void)ws_size;
  const float* x  = (const float*)d_in[0];
  const float* Wq = (const float*)d_in[1];
  const float* bq = (const float*)d_in[2];
  const float* Wk = (const float*)d_in[3];
  const float* bk = (const float*)d_in[4];
  const float* Wv = (const float*)d_in[5];
  const float* bv = (const float*)d_in[6];
  const float* Wo = (const float*)d_in[7];
  const float* bo = (const float*)d_in[8];
  const int* dil  = (const int*)d_in[9];
  float* out = (float*)d_out;

  char* ws = (char*)d_ws;
  u16* xh  = (u16*)ws;  ws += (size_t)Mm * Kk * 2;             // 8 MB  [m][d] f16
  u16* wT  = (u16*)ws;  ws += (size_t)24 * Ee * Kk * 2;        // 6 MB  [proj*8+h][e][d] f16
  u16* woT = (u16*)ws;  ws += (size_t)Kk * Dd * 2;             // 2 MB  [d][h*E+e] f16
  u16* q = (u16*)ws; ws += (size_t)Bb * Hh * Ss * Ee * 2;      // 8 MB each, f16 [bh][s][e]
  u16* k = (u16*)ws; ws += (size_t)Bb * Hh * Ss * Ee * 2;
  u16* v = (u16*)ws; ws += (size_t)Bb * Hh * Ss * Ee * 2;
  // attn (8 MB f16) aliases xh — dead after gemm_qkv (stream-ordered)
  u16* attn = xh;

  cast_f32_f16<<<(Mm * Kk) / 1024, 256, 0, stream>>>(x, xh, Mm * Kk);
  dim3 tb(32, 8);
  transpose_qkv<<<dim3(Dd / 32, Ee / 32, 24), tb, 0, stream>>>(Wq, Wk, Wv, wT);
  transpose_wo<<<dim3((Hh * Ee) / 32, Dd / 32, 1), tb, 0, stream>>>(Wo, woT);

  gemm_qkv<<<dim3(Mm / 128, 1, 24), 256, 0, stream>>>(xh, wT, bq, bk, bv, q, k, v);
  attn_kernel<<<(Bb * Hh * Ss) / 4, 256, 0, stream>>>(q, k, v, bk, bv, dil, attn);
  gemm_out<<<dim3(Mm / 64, Dd / 128), 256, 0, stream>>>(attn, woT, bo, out);
}